// Round 16
// baseline (442.582 us; speedup 1.0000x reference)
//
#include <hip/hip_runtime.h>
#include <hip/hip_bf16.h>

#define B_ 4
#define C_ 512
#define L_ 2048
#define H_ 8
#define E_ 64
// sqrt(0.125 * log2(e)) — folded into Q (and K=Q) so QK^T yields log2-domain scores
#define QSCALE 0.4246609f
#define NUNITS_B 256   // units per batch: 8 h x 32 qt

typedef __attribute__((ext_vector_type(8))) short bf16x8;
typedef __attribute__((ext_vector_type(4))) float f32x4;
typedef __attribute__((ext_vector_type(4))) unsigned short u16x4;

static __device__ __forceinline__ unsigned short f2bf(float f) {
    union { float f; unsigned u; } v; v.f = f;
    unsigned r = v.u + 0x7FFFu + ((v.u >> 16) & 1u);
    return (unsigned short)(r >> 16);
}

// light barrier: make LDS writes visible, do NOT drain vmcnt (loads stay in flight)
#define LBAR() do { asm volatile("s_waitcnt lgkmcnt(0)" ::: "memory"); \
                    __builtin_amdgcn_s_barrier(); } while (0)

// ---------------- Pass A: cast x -> xb (bf16, [b][c][l]) and xt (bf16, [b][l][c]) ----------------
__global__ __launch_bounds__(256) void prep_kernel(const float* __restrict__ x,
                                                   unsigned short* __restrict__ xb,
                                                   unsigned short* __restrict__ xt) {
    const int lt = blockIdx.x, ct = blockIdx.y, b = blockIdx.z;
    const int l0 = lt * 64, c0 = ct * 64;
    const int t = threadIdx.x;
    __shared__ unsigned short T[64 * 72];

    const int cl = t >> 2, lo = (t & 3) * 16;
    const float* src = x + ((size_t)(b * C_ + c0 + cl)) * L_ + l0 + lo;
    unsigned short u[16];
    #pragma unroll
    for (int j = 0; j < 16; j += 4) {
        float4 v = *reinterpret_cast<const float4*>(src + j);
        u[j] = f2bf(v.x); u[j + 1] = f2bf(v.y); u[j + 2] = f2bf(v.z); u[j + 3] = f2bf(v.w);
    }
    unsigned short* xbp = xb + ((size_t)(b * C_ + c0 + cl)) * L_ + l0 + lo;
    reinterpret_cast<uint4*>(xbp)[0] = reinterpret_cast<uint4*>(u)[0];
    reinterpret_cast<uint4*>(xbp)[1] = reinterpret_cast<uint4*>(u)[1];
    reinterpret_cast<uint4*>(&T[cl * 72 + lo])[0] = reinterpret_cast<uint4*>(u)[0];
    reinterpret_cast<uint4*>(&T[cl * 72 + lo + 8])[0] = reinterpret_cast<uint4*>(u)[1];
    __syncthreads();
    const int ll = t >> 2, co = (t & 3) * 16;
    unsigned short v16[16];
    #pragma unroll
    for (int j = 0; j < 16; ++j) v16[j] = T[(co + j) * 72 + ll];
    unsigned short* xtp = xt + ((size_t)b * L_ + l0 + ll) * C_ + c0 + co;
    reinterpret_cast<uint4*>(xtp)[0] = reinterpret_cast<uint4*>(v16)[0];
    reinterpret_cast<uint4*>(xtp)[1] = reinterpret_cast<uint4*>(v16)[1];
}

// ---------------- Pass A2: cast W fp32 -> bf16 ----------------
__global__ __launch_bounds__(256) void wcast_kernel(const float* __restrict__ W,
                                                    unsigned short* __restrict__ Wb) {
    const int i = blockIdx.x * 256 + threadIdx.x;
    float4 v = reinterpret_cast<const float4*>(W)[i];
    union { unsigned short u[4]; unsigned long long ll; } o;
    o.u[0] = f2bf(v.x); o.u[1] = f2bf(v.y); o.u[2] = f2bf(v.z); o.u[3] = f2bf(v.w);
    reinterpret_cast<unsigned long long*>(Wb)[i] = o.ll;
}

// ---------------- Pass B: Q = (W x + b) * QSCALE, bf16 [(b*H+h)][l][e] ----------------
__global__ __launch_bounds__(256) void proj_kernel(const unsigned short* __restrict__ Wb,
                                                   const float* __restrict__ bq,
                                                   const unsigned short* __restrict__ xt,
                                                   unsigned short* __restrict__ qb) {
    const int lt = blockIdx.x, h = blockIdx.y, b = blockIdx.z;
    const int tid = threadIdx.x, w = tid >> 6, lane = tid & 63;
    const int lr = lane & 15, lg = lane >> 4;
    const int l = lt * 64 + w * 16 + lr;
    const int o0 = h * 64;

    f32x4 acc[4] = {};
    const unsigned short* xrow = xt + ((size_t)b * L_ + l) * C_;
    for (int ks = 0; ks < 16; ++ks) {
        bf16x8 bf = *reinterpret_cast<const bf16x8*>(xrow + ks * 32 + lg * 8);
        #pragma unroll
        for (int mt = 0; mt < 4; ++mt) {
            bf16x8 af = *reinterpret_cast<const bf16x8*>(Wb + (size_t)(o0 + mt * 16 + lr) * C_ + ks * 32 + lg * 8);
            acc[mt] = __builtin_amdgcn_mfma_f32_16x16x32_bf16(af, bf, acc[mt], 0, 0, 0);
        }
    }
    const int bh = b * H_ + h;
    unsigned short* qrow = qb + ((size_t)bh * L_ + l) * 64;
    #pragma unroll
    for (int mt = 0; mt < 4; ++mt) {
        const int e0 = mt * 16 + lg * 4;
        const float4 bb = *reinterpret_cast<const float4*>(bq + o0 + e0);
        union { unsigned short u[4]; unsigned long long ll; } o;
        o.u[0] = f2bf((acc[mt][0] + bb.x) * QSCALE);
        o.u[1] = f2bf((acc[mt][1] + bb.y) * QSCALE);
        o.u[2] = f2bf((acc[mt][2] + bb.z) * QSCALE);
        o.u[3] = f2bf((acc[mt][3] + bb.w) * QSCALE);
        *reinterpret_cast<unsigned long long*>(qrow + e0) = o.ll;
    }
}

// ---------------- Pass C: fused attention, KBLK=512, unrolled PV, 2-bank V ring ----------------
// V loads for 32k-step at k-offset KOFF into bank BK (4 x b128, wave's 64 channels)
#define LDVB(BK, KOFF)                                                                  \
    {                                                                                   \
        _Pragma("unroll")                                                               \
        for (int ct = 0; ct < 4; ++ct)                                                  \
            pvv[BK][ct] = *reinterpret_cast<const bf16x8*>(                             \
                Vbase + (size_t)(c0w + ct * 16 + lr) * L_ + (KOFF) + lg * 8);           \
    }

// PV step S_: consume bank CUR; prefetch step S_+1 into bank NXT; 16 MFMAs
#define PV_STEP(CUR, NXT, S_, KSMAX_)                                                   \
    {                                                                                   \
        if ((S_) + 1 < (KSMAX_)) LDVB(NXT, k0 + ((S_) + 1) * 32)                        \
        bf16x8 pa[4];                                                                   \
        _Pragma("unroll")                                                               \
        for (int mt = 0; mt < 4; ++mt) {                                                \
            const int row = mt * 16 + lr;                                               \
            const int g2 = ((S_) * 4 + lg) ^ (lr & 7);                                  \
            pa[mt] = *reinterpret_cast<const bf16x8*>(&P[row * 512 + (g2 << 3)]);       \
        }                                                                               \
        __builtin_amdgcn_s_setprio(1);                                                  \
        _Pragma("unroll")                                                               \
        for (int mt = 0; mt < 4; ++mt)                                                  \
            _Pragma("unroll")                                                           \
            for (int ct = 0; ct < 4; ++ct)                                              \
                acc[mt][ct] = __builtin_amdgcn_mfma_f32_16x16x32_bf16(                  \
                    pa[mt], pvv[CUR][ct], acc[mt][ct], 0, 0, 0);                        \
        __builtin_amdgcn_s_setprio(0);                                                  \
    }

// S phase body: MASKED = 0 (wave fully below diagonal) skips all compare/select VALU
#define S_PHASE(MASKED)                                                                          \
    {                                                                                            \
        bf16x8 kb[4][2];                                                                         \
        _Pragma("unroll")                                                                        \
        for (int ksub = 0; ksub < 4; ++ksub) {                                                   \
            const size_t krow = (size_t)(kw0 + ksub * 16 + lr) * 64;                             \
            kb[ksub][0] = *reinterpret_cast<const bf16x8*>(Qbase + krow + lg * 8);               \
            kb[ksub][1] = *reinterpret_cast<const bf16x8*>(Qbase + krow + 32 + lg * 8);          \
        }                                                                                        \
        _Pragma("unroll")                                                                        \
        for (int nt = 0; nt < 4; ++nt) {                                                         \
            const int qrow = nt * 16 + lr;                                                       \
            bf16x8 aq0 = *reinterpret_cast<const bf16x8*>(&Qt[qrow * 64 + ((lg ^ (lr & 7)) << 3)]);        \
            bf16x8 aq1 = *reinterpret_cast<const bf16x8*>(&Qt[qrow * 64 + (((4 + lg) ^ (lr & 7)) << 3)]);  \
            const int q = q0 + qrow;                                                             \
            _Pragma("unroll")                                                                    \
            for (int ksub = 0; ksub < 4; ++ksub) {                                               \
                f32x4 z = {};                                                                    \
                z = __builtin_amdgcn_mfma_f32_16x16x32_bf16(kb[ksub][0], aq0, z, 0, 0, 0);       \
                z = __builtin_amdgcn_mfma_f32_16x16x32_bf16(kb[ksub][1], aq1, z, 0, 0, 0);       \
                float p0, p1, p2, p3;                                                            \
                if (MASKED) {                                                                    \
                    const int kbase = kw0 + ksub * 16 + lg * 4;                                  \
                    p0 = (kbase + 0 <= q) ? __builtin_amdgcn_exp2f(z[0]) : 0.f;                  \
                    p1 = (kbase + 1 <= q) ? __builtin_amdgcn_exp2f(z[1]) : 0.f;                  \
                    p2 = (kbase + 2 <= q) ? __builtin_amdgcn_exp2f(z[2]) : 0.f;                  \
                    p3 = (kbase + 3 <= q) ? __builtin_amdgcn_exp2f(z[3]) : 0.f;                  \
                } else {                                                                         \
                    p0 = __builtin_amdgcn_exp2f(z[0]);                                           \
                    p1 = __builtin_amdgcn_exp2f(z[1]);                                           \
                    p2 = __builtin_amdgcn_exp2f(z[2]);                                           \
                    p3 = __builtin_amdgcn_exp2f(z[3]);                                           \
                }                                                                                \
                rs[nt] += (p0 + p1) + (p2 + p3);                                                 \
                unsigned r01, r23;                                                               \
                asm("v_cvt_pk_bf16_f32 %0, %1, %2" : "=v"(r01) : "v"(p0), "v"(p1));              \
                asm("v_cvt_pk_bf16_f32 %0, %1, %2" : "=v"(r23) : "v"(p2), "v"(p3));              \
                const int kl = w * 64 + ksub * 16 + lg * 4;                                      \
                const int gg = (kl >> 3) ^ (qrow & 7);                                           \
                const unsigned long long pk = ((unsigned long long)r23 << 32) | r01;             \
                *reinterpret_cast<unsigned long long*>(&P[qrow * 512 + (gg << 3) + (kl & 7)]) = pk; \
            }                                                                                    \
        }                                                                                        \
    }

__global__ __launch_bounds__(512, 4) void pv_kernel(const unsigned short* __restrict__ qb,
                                                    const unsigned short* __restrict__ xb,
                                                    float* __restrict__ out,
                                                    int* __restrict__ counters) {
    const int tid = threadIdx.x, w = tid >> 6, lane = tid & 63;
    const int lr = lane & 15, lg = lane >> 4;
    const int c0w = w * 64;                      // PV: this wave's 64-channel slice
    // batch pinned by blockIdx (XCD round-robin heuristic): 128 blocks per batch
    const int myb = (blockIdx.x & 7) >> 1;

    __shared__ unsigned short Qt[64 * 64];       // swizzled Q tile (8 KB)
    __shared__ unsigned short P[64 * 512];       // 64q x 512k bf16, XOR-swizzled (64 KB)
    __shared__ float rsT[64][8];                 // per-S-wave rowsum partials (2 KB)
    __shared__ int s_u;

    const int b = myb;
    const unsigned short* Vbase = xb + (size_t)b * C_ * L_;

    for (;;) {
        __syncthreads();   // previous unit's readers of Qt/P/rsT/s_u are done
        if (tid == 0) s_u = atomicAdd(counters + myb, 1);
        __syncthreads();
        const int u = s_u;
        if (u >= NUNITS_B) return;

        // heavy q-tiles first (LPT packing on the per-batch dynamic queue)
        const int qt = 31 - (u >> 3);
        const int h = u & 7;
        const int q0 = qt * 64, qlim = q0 + 63;
        const int nkt = (q0 >> 9) + 1;           // KBLK = 512
        const int bh = b * H_ + h;
        const unsigned short* Qbase = qb + (size_t)bh * L_ * 64;

        // stage Q tile (64 rows x 64 e) into LDS, granule g -> g ^ (row&7)
        {
            const int r = tid >> 3, g = tid & 7;
            bf16x8 v = *reinterpret_cast<const bf16x8*>(Qbase + (size_t)(q0 + r) * 64 + g * 8);
            *reinterpret_cast<bf16x8*>(&Qt[r * 64 + ((g ^ (r & 7)) << 3)]) = v;
        }

        bf16x8 pvv[2][4];                        // 2-bank V ring, distance-1 (L2-resident V)
        f32x4 acc[4][4] = {};
        float rs[4] = {0.f, 0.f, 0.f, 0.f};

        LBAR();   // Qt visible

        #pragma unroll 1
        for (int kt = 0; kt < nkt; ++kt) {
            const int k0 = kt * 512;
            const int ksmax = min(16, ((qlim - k0) >> 5) + 1);   // even, 2..16
            const int kw0 = k0 + w * 64;                          // S: wave's 64k slice

            LDVB(0, k0)   // PV step-0 V loads issued under the S phase

            // ---- S phase: wave computes 64q x 64k slice of S, exp, pack to P ----
            if (kw0 + 63 < q0) {
                S_PHASE(0)            // fully below diagonal: no mask VALU
            } else if (kw0 <= qlim) {
                S_PHASE(1)            // diagonal slice: masked
            }
            LBAR();   // P visible; V bank-0 loads stay in flight

            // ---- PV phase: interior kts take the fully-unrolled 16-step path ----
            if (ksmax == 16) {
                #pragma unroll
                for (int s = 0; s < 16; ++s) {
                    PV_STEP(s & 1, (s + 1) & 1, s, 16)
                }
            } else {
                #pragma unroll 1
                for (int s = 0; s < ksmax; s += 2) {
                    PV_STEP(0, 1, s, ksmax)
                    PV_STEP(1, 0, s + 1, ksmax)
                }
            }
            LBAR();   // P consumed; next kt's S may overwrite
        }

        // rowsum: reduce over lg, publish per-wave partials, merge
        #pragma unroll
        for (int nt = 0; nt < 4; ++nt) {
            float t0 = __shfl_xor(rs[nt], 16); rs[nt] += t0;
            float t1 = __shfl_xor(rs[nt], 32); rs[nt] += t1;
        }
        if (lg == 0) {
            #pragma unroll
            for (int nt = 0; nt < 4; ++nt) rsT[nt * 16 + lr][w] = rs[nt];
        }
        LBAR();

        // epilogue: li per q, bf16 residual, NT streaming stores
        const unsigned short* xres = xb + (size_t)b * C_ * L_;
        float* ob = out + (size_t)bh * C_ * L_;
        #pragma unroll
        for (int mt = 0; mt < 4; ++mt) {
            f32x4 li;
            #pragma unroll
            for (int r = 0; r < 4; ++r) {
                const f32x4 s0 = *reinterpret_cast<const f32x4*>(&rsT[mt * 16 + lg * 4 + r][0]);
                const f32x4 s1 = *reinterpret_cast<const f32x4*>(&rsT[mt * 16 + lg * 4 + r][4]);
                li[r] = 1.f / (((s0[0] + s0[1]) + (s0[2] + s0[3])) + ((s1[0] + s1[1]) + (s1[2] + s1[3])));
            }
            const int lbase = q0 + mt * 16 + lg * 4;
            #pragma unroll
            for (int ct = 0; ct < 4; ++ct) {
                const int c = c0w + ct * 16 + lr;
                const u16x4 rv = __builtin_nontemporal_load(
                    reinterpret_cast<const u16x4*>(xres + (size_t)c * L_ + lbase));
                f32x4 o;
                o[0] = acc[mt][ct][0] * li[0] + __uint_as_float((unsigned)rv[0] << 16);
                o[1] = acc[mt][ct][1] * li[1] + __uint_as_float((unsigned)rv[1] << 16);
                o[2] = acc[mt][ct][2] * li[2] + __uint_as_float((unsigned)rv[2] << 16);
                o[3] = acc[mt][ct][3] * li[3] + __uint_as_float((unsigned)rv[3] << 16);
                __builtin_nontemporal_store(o, reinterpret_cast<f32x4*>(ob + (size_t)c * L_ + lbase));
            }
        }
    }
}

extern "C" void kernel_launch(void* const* d_in, const int* in_sizes, int n_in,
                              void* d_out, int out_size, void* d_ws, size_t ws_size,
                              hipStream_t stream) {
    const float* x  = (const float*)d_in[0];
    const float* Wq = (const float*)d_in[1];
    const float* bq = (const float*)d_in[2];
    float* out = (float*)d_out;

    unsigned short* xb   = (unsigned short*)d_ws;                        // B*C*L bf16   = 8 MiB
    unsigned short* xt   = xb + (size_t)B_ * C_ * L_;                    // B*L*C bf16   = 8 MiB
    unsigned short* qbuf = xt + (size_t)B_ * L_ * C_;                    // B*H*L*E bf16 = 8 MiB
    unsigned short* Wb   = qbuf + (size_t)B_ * H_ * L_ * E_;             // 512 KiB
    int* counters = (int*)(Wb + (size_t)H_ * E_ * C_);                   // 16 B (one per batch)

    (void)hipMemsetAsync(counters, 0, 16, stream);
    prep_kernel<<<dim3(32, 8, 4), 256, 0, stream>>>(x, xb, xt);
    wcast_kernel<<<dim3(256), 256, 0, stream>>>(Wq, Wb);
    proj_kernel<<<dim3(32, 8, 4), 256, 0, stream>>>(Wb, bq, xt, qbuf);
    pv_kernel<<<dim3(512), 512, 0, stream>>>(qbuf, xb, out, counters);
}

// Round 17
// 433.103 us; speedup vs baseline: 1.0219x; 1.0219x over previous
//
#include <hip/hip_runtime.h>
#include <hip/hip_bf16.h>

#define B_ 4
#define C_ 512
#define L_ 2048
#define H_ 8
#define E_ 64
// sqrt(0.125 * log2(e)) — folded into Q (and K=Q) so QK^T yields log2-domain scores
#define QSCALE 0.4246609f
#define NUNITS_B 256   // units per batch: 8 h x 32 qt

typedef __attribute__((ext_vector_type(8))) short bf16x8;
typedef __attribute__((ext_vector_type(4))) float f32x4;
typedef __attribute__((ext_vector_type(4))) unsigned short u16x4;

static __device__ __forceinline__ unsigned short f2bf(float f) {
    union { float f; unsigned u; } v; v.f = f;
    unsigned r = v.u + 0x7FFFu + ((v.u >> 16) & 1u);
    return (unsigned short)(r >> 16);
}

// light barrier: make LDS writes visible, do NOT drain vmcnt (loads stay in flight)
#define LBAR() do { asm volatile("s_waitcnt lgkmcnt(0)" ::: "memory"); \
                    __builtin_amdgcn_s_barrier(); } while (0)

// ---------------- Pass A: cast x -> xb (bf16, [b][c][l]) and xt (bf16, [b][l][c]) ----------------
__global__ __launch_bounds__(256) void prep_kernel(const float* __restrict__ x,
                                                   unsigned short* __restrict__ xb,
                                                   unsigned short* __restrict__ xt) {
    const int lt = blockIdx.x, ct = blockIdx.y, b = blockIdx.z;
    const int l0 = lt * 64, c0 = ct * 64;
    const int t = threadIdx.x;
    __shared__ unsigned short T[64 * 72];

    const int cl = t >> 2, lo = (t & 3) * 16;
    const float* src = x + ((size_t)(b * C_ + c0 + cl)) * L_ + l0 + lo;
    unsigned short u[16];
    #pragma unroll
    for (int j = 0; j < 16; j += 4) {
        float4 v = *reinterpret_cast<const float4*>(src + j);
        u[j] = f2bf(v.x); u[j + 1] = f2bf(v.y); u[j + 2] = f2bf(v.z); u[j + 3] = f2bf(v.w);
    }
    unsigned short* xbp = xb + ((size_t)(b * C_ + c0 + cl)) * L_ + l0 + lo;
    reinterpret_cast<uint4*>(xbp)[0] = reinterpret_cast<uint4*>(u)[0];
    reinterpret_cast<uint4*>(xbp)[1] = reinterpret_cast<uint4*>(u)[1];
    reinterpret_cast<uint4*>(&T[cl * 72 + lo])[0] = reinterpret_cast<uint4*>(u)[0];
    reinterpret_cast<uint4*>(&T[cl * 72 + lo + 8])[0] = reinterpret_cast<uint4*>(u)[1];
    __syncthreads();
    const int ll = t >> 2, co = (t & 3) * 16;
    unsigned short v16[16];
    #pragma unroll
    for (int j = 0; j < 16; ++j) v16[j] = T[(co + j) * 72 + ll];
    unsigned short* xtp = xt + ((size_t)b * L_ + l0 + ll) * C_ + c0 + co;
    reinterpret_cast<uint4*>(xtp)[0] = reinterpret_cast<uint4*>(v16)[0];
    reinterpret_cast<uint4*>(xtp)[1] = reinterpret_cast<uint4*>(v16)[1];
}

// ---------------- Pass A2: cast W fp32 -> bf16 ----------------
__global__ __launch_bounds__(256) void wcast_kernel(const float* __restrict__ W,
                                                    unsigned short* __restrict__ Wb) {
    const int i = blockIdx.x * 256 + threadIdx.x;
    float4 v = reinterpret_cast<const float4*>(W)[i];
    union { unsigned short u[4]; unsigned long long ll; } o;
    o.u[0] = f2bf(v.x); o.u[1] = f2bf(v.y); o.u[2] = f2bf(v.z); o.u[3] = f2bf(v.w);
    reinterpret_cast<unsigned long long*>(Wb)[i] = o.ll;
}

// ---------------- Pass B: Q = (W x + b) * QSCALE, bf16 [(b*H+h)][l][e] ----------------
__global__ __launch_bounds__(256) void proj_kernel(const unsigned short* __restrict__ Wb,
                                                   const float* __restrict__ bq,
                                                   const unsigned short* __restrict__ xt,
                                                   unsigned short* __restrict__ qb) {
    const int lt = blockIdx.x, h = blockIdx.y, b = blockIdx.z;
    const int tid = threadIdx.x, w = tid >> 6, lane = tid & 63;
    const int lr = lane & 15, lg = lane >> 4;
    const int l = lt * 64 + w * 16 + lr;
    const int o0 = h * 64;

    f32x4 acc[4] = {};
    const unsigned short* xrow = xt + ((size_t)b * L_ + l) * C_;
    for (int ks = 0; ks < 16; ++ks) {
        bf16x8 bf = *reinterpret_cast<const bf16x8*>(xrow + ks * 32 + lg * 8);
        #pragma unroll
        for (int mt = 0; mt < 4; ++mt) {
            bf16x8 af = *reinterpret_cast<const bf16x8*>(Wb + (size_t)(o0 + mt * 16 + lr) * C_ + ks * 32 + lg * 8);
            acc[mt] = __builtin_amdgcn_mfma_f32_16x16x32_bf16(af, bf, acc[mt], 0, 0, 0);
        }
    }
    const int bh = b * H_ + h;
    unsigned short* qrow = qb + ((size_t)bh * L_ + l) * 64;
    #pragma unroll
    for (int mt = 0; mt < 4; ++mt) {
        const int e0 = mt * 16 + lg * 4;
        const float4 bb = *reinterpret_cast<const float4*>(bq + o0 + e0);
        union { unsigned short u[4]; unsigned long long ll; } o;
        o.u[0] = f2bf((acc[mt][0] + bb.x) * QSCALE);
        o.u[1] = f2bf((acc[mt][1] + bb.y) * QSCALE);
        o.u[2] = f2bf((acc[mt][2] + bb.z) * QSCALE);
        o.u[3] = f2bf((acc[mt][3] + bb.w) * QSCALE);
        *reinterpret_cast<unsigned long long*>(qrow + e0) = o.ll;
    }
}

// ---------------- Pass C: fused attention, KBLK=512, 4-bank V ring, K prefetch ----------------
// V loads for 32k-step at k-offset KOFF into bank BK (4 x b128, wave's 64 channels)
#define LDVB(BK, KOFF)                                                                  \
    {                                                                                   \
        _Pragma("unroll")                                                               \
        for (int ct = 0; ct < 4; ++ct)                                                  \
            pvv[BK][ct] = *reinterpret_cast<const bf16x8*>(                             \
                Vbase + (size_t)(c0w + ct * 16 + lr) * L_ + (KOFF) + lg * 8);           \
    }

// PV step S_: consume bank CUR, prefetch step S_+2 into bank NXT; 16 MFMAs
#define PV_STEP(CUR, NXT, S_, KSMAX_)                                                   \
    {                                                                                   \
        if ((S_) + 2 < (KSMAX_)) LDVB(NXT, k0 + ((S_) + 2) * 32)                        \
        bf16x8 pa[4];                                                                   \
        _Pragma("unroll")                                                               \
        for (int mt = 0; mt < 4; ++mt) {                                                \
            const int row = mt * 16 + lr;                                               \
            const int g2 = ((S_) * 4 + lg) ^ (lr & 7);                                  \
            pa[mt] = *reinterpret_cast<const bf16x8*>(&P[row * 512 + (g2 << 3)]);       \
        }                                                                               \
        __builtin_amdgcn_s_setprio(1);                                                  \
        _Pragma("unroll")                                                               \
        for (int mt = 0; mt < 4; ++mt)                                                  \
            _Pragma("unroll")                                                           \
            for (int ct = 0; ct < 4; ++ct)                                              \
                acc[mt][ct] = __builtin_amdgcn_mfma_f32_16x16x32_bf16(                  \
                    pa[mt], pvv[CUR][ct], acc[mt][ct], 0, 0, 0);                        \
        __builtin_amdgcn_s_setprio(0);                                                  \
    }

// S phase body: MASKED = 0 (wave fully below diagonal) skips all compare/select VALU.
// Uses loop-carried kb[][] (prefetched during previous kt's PV phase).
#define S_PHASE(MASKED)                                                                          \
    {                                                                                            \
        _Pragma("unroll")                                                                        \
        for (int nt = 0; nt < 4; ++nt) {                                                         \
            const int qrow = nt * 16 + lr;                                                       \
            bf16x8 aq0 = *reinterpret_cast<const bf16x8*>(&Qt[qrow * 64 + ((lg ^ (lr & 7)) << 3)]);        \
            bf16x8 aq1 = *reinterpret_cast<const bf16x8*>(&Qt[qrow * 64 + (((4 + lg) ^ (lr & 7)) << 3)]);  \
            const int q = q0 + qrow;                                                             \
            _Pragma("unroll")                                                                    \
            for (int ksub = 0; ksub < 4; ++ksub) {                                               \
                f32x4 z = {};                                                                    \
                z = __builtin_amdgcn_mfma_f32_16x16x32_bf16(kb[ksub][0], aq0, z, 0, 0, 0);       \
                z = __builtin_amdgcn_mfma_f32_16x16x32_bf16(kb[ksub][1], aq1, z, 0, 0, 0);       \
                float p0, p1, p2, p3;                                                            \
                if (MASKED) {                                                                    \
                    const int kbase = kw0 + ksub * 16 + lg * 4;                                  \
                    p0 = (kbase + 0 <= q) ? __builtin_amdgcn_exp2f(z[0]) : 0.f;                  \
                    p1 = (kbase + 1 <= q) ? __builtin_amdgcn_exp2f(z[1]) : 0.f;                  \
                    p2 = (kbase + 2 <= q) ? __builtin_amdgcn_exp2f(z[2]) : 0.f;                  \
                    p3 = (kbase + 3 <= q) ? __builtin_amdgcn_exp2f(z[3]) : 0.f;                  \
                } else {                                                                         \
                    p0 = __builtin_amdgcn_exp2f(z[0]);                                           \
                    p1 = __builtin_amdgcn_exp2f(z[1]);                                           \
                    p2 = __builtin_amdgcn_exp2f(z[2]);                                           \
                    p3 = __builtin_amdgcn_exp2f(z[3]);                                           \
                }                                                                                \
                rs[nt] += (p0 + p1) + (p2 + p3);                                                 \
                unsigned r01, r23;                                                               \
                asm("v_cvt_pk_bf16_f32 %0, %1, %2" : "=v"(r01) : "v"(p0), "v"(p1));              \
                asm("v_cvt_pk_bf16_f32 %0, %1, %2" : "=v"(r23) : "v"(p2), "v"(p3));              \
                const int kl = w * 64 + ksub * 16 + lg * 4;                                      \
                const int gg = (kl >> 3) ^ (qrow & 7);                                           \
                const unsigned long long pk = ((unsigned long long)r23 << 32) | r01;             \
                *reinterpret_cast<unsigned long long*>(&P[qrow * 512 + (gg << 3) + (kl & 7)]) = pk; \
            }                                                                                    \
        }                                                                                        \
    }

// K-slab loads for the k-tile whose wave slice starts at row KW (8 x b128)
#define LDK(KW)                                                                         \
    {                                                                                   \
        _Pragma("unroll")                                                               \
        for (int ksub = 0; ksub < 4; ++ksub) {                                          \
            const size_t krow = (size_t)((KW) + ksub * 16 + lr) * 64;                   \
            kb[ksub][0] = *reinterpret_cast<const bf16x8*>(Qbase + krow + lg * 8);      \
            kb[ksub][1] = *reinterpret_cast<const bf16x8*>(Qbase + krow + 32 + lg * 8); \
        }                                                                               \
    }

__global__ __launch_bounds__(512, 2) void pv_kernel(const unsigned short* __restrict__ qb,
                                                    const unsigned short* __restrict__ xb,
                                                    float* __restrict__ out,
                                                    int* __restrict__ counters) {
    const int tid = threadIdx.x, w = tid >> 6, lane = tid & 63;
    const int lr = lane & 15, lg = lane >> 4;
    const int c0w = w * 64;                      // PV: this wave's 64-channel slice
    // batch pinned by blockIdx (XCD round-robin heuristic): 128 blocks per batch
    const int myb = (blockIdx.x & 7) >> 1;

    __shared__ unsigned short Qt[64 * 64];       // swizzled Q tile (8 KB)
    __shared__ unsigned short P[64 * 512];       // 64q x 512k bf16, XOR-swizzled (64 KB)
    __shared__ float rsT[64][8];                 // per-S-wave rowsum partials (2 KB)
    __shared__ int s_u;

    const int b = myb;
    const unsigned short* Vbase = xb + (size_t)b * C_ * L_;

    for (;;) {
        // WAR on s_u only — plain barrier, NO vmcnt drain (NT stores stay in flight)
        __builtin_amdgcn_s_barrier();
        if (tid == 0) s_u = atomicAdd(counters + myb, 1);
        LBAR();   // s_u visible
        const int u = s_u;
        if (u >= NUNITS_B) return;

        // heavy q-tiles first (LPT packing on the per-batch dynamic queue)
        const int qt = 31 - (u >> 3);
        const int h = u & 7;
        const int q0 = qt * 64, qlim = q0 + 63;
        const int nkt = (q0 >> 9) + 1;           // KBLK = 512
        const int bh = b * H_ + h;
        const unsigned short* Qbase = qb + (size_t)bh * L_ * 64;

        // stage Q tile (64 rows x 64 e) into LDS, granule g -> g ^ (row&7)
        {
            const int r = tid >> 3, g = tid & 7;
            bf16x8 v = *reinterpret_cast<const bf16x8*>(Qbase + (size_t)(q0 + r) * 64 + g * 8);
            *reinterpret_cast<bf16x8*>(&Qt[r * 64 + ((g ^ (r & 7)) << 3)]) = v;
        }

        bf16x8 pvv[4][4];                        // 4-bank V ring, distance-2 prefetch
        bf16x8 kb[4][2];                         // loop-carried K slab (prefetched in PV)
        f32x4 acc[4][4] = {};
        float rs[4] = {0.f, 0.f, 0.f, 0.f};

        LDK(w * 64)                              // prologue K for kt=0

        LBAR();   // Qt visible; K/V preloads stay in flight

        #pragma unroll 1
        for (int kt = 0; kt < nkt; ++kt) {
            const int k0 = kt * 512;
            const int ksmax = min(16, ((qlim - k0) >> 5) + 1);   // even, 2..16
            const int kw0 = k0 + w * 64;                          // S: wave's 64k slice

            LDVB(0, k0)          // PV steps 0,1 V loads issued under the S phase
            LDVB(1, k0 + 32)

            // ---- S phase: wave computes 64q x 64k slice of S, exp, pack to P ----
            if (kw0 + 63 <= q0) {
                S_PHASE(0)            // fully below diagonal: no mask VALU
            } else if (kw0 <= qlim) {
                S_PHASE(1)            // diagonal slice: masked
            }
            LBAR();   // P visible; V bank-0/1 loads stay in flight

            // ---- PV phase ----
            if (ksmax == 16) {
                PV_STEP(0, 2, 0, 16)
                PV_STEP(1, 3, 1, 16)
                if (kt + 1 < nkt) LDK(k0 + 512 + w * 64)   // next-kt K under PV
                PV_STEP(2, 0, 2, 16)
                PV_STEP(3, 1, 3, 16)
                PV_STEP(0, 2, 4, 16)
                PV_STEP(1, 3, 5, 16)
                PV_STEP(2, 0, 6, 16)
                PV_STEP(3, 1, 7, 16)
                PV_STEP(0, 2, 8, 16)
                PV_STEP(1, 3, 9, 16)
                PV_STEP(2, 0, 10, 16)
                PV_STEP(3, 1, 11, 16)
                PV_STEP(0, 2, 12, 16)
                PV_STEP(1, 3, 13, 16)
                PV_STEP(2, 0, 14, 16)
                PV_STEP(3, 1, 15, 16)
            } else {
                // last kt only (ksmax < 16): no next kt, no K prefetch needed
                int s = 0;
                #pragma unroll 1
                for (; s + 4 <= ksmax; s += 4) {
                    PV_STEP(0, 2, s, ksmax)
                    PV_STEP(1, 3, s + 1, ksmax)
                    PV_STEP(2, 0, s + 2, ksmax)
                    PV_STEP(3, 1, s + 3, ksmax)
                }
                if (s < ksmax) {
                    PV_STEP(0, 2, s, ksmax)
                    PV_STEP(1, 3, s + 1, ksmax)
                }
            }
            LBAR();   // P consumed; next kt's S may overwrite
        }

        // rowsum: reduce over lg, publish per-wave partials, merge
        #pragma unroll
        for (int nt = 0; nt < 4; ++nt) {
            float t0 = __shfl_xor(rs[nt], 16); rs[nt] += t0;
            float t1 = __shfl_xor(rs[nt], 32); rs[nt] += t1;
        }
        if (lg == 0) {
            #pragma unroll
            for (int nt = 0; nt < 4; ++nt) rsT[nt * 16 + lr][w] = rs[nt];
        }
        LBAR();

        // epilogue: li per q, bf16 residual, NT streaming stores
        const unsigned short* xres = xb + (size_t)b * C_ * L_;
        float* ob = out + (size_t)bh * C_ * L_;
        #pragma unroll
        for (int mt = 0; mt < 4; ++mt) {
            f32x4 li;
            #pragma unroll
            for (int r = 0; r < 4; ++r) {
                const f32x4 s0 = *reinterpret_cast<const f32x4*>(&rsT[mt * 16 + lg * 4 + r][0]);
                const f32x4 s1 = *reinterpret_cast<const f32x4*>(&rsT[mt * 16 + lg * 4 + r][4]);
                li[r] = 1.f / (((s0[0] + s0[1]) + (s0[2] + s0[3])) + ((s1[0] + s1[1]) + (s1[2] + s1[3])));
            }
            const int lbase = q0 + mt * 16 + lg * 4;
            #pragma unroll
            for (int ct = 0; ct < 4; ++ct) {
                const int c = c0w + ct * 16 + lr;
                const u16x4 rv = __builtin_nontemporal_load(
                    reinterpret_cast<const u16x4*>(xres + (size_t)c * L_ + lbase));
                f32x4 o;
                o[0] = acc[mt][ct][0] * li[0] + __uint_as_float((unsigned)rv[0] << 16);
                o[1] = acc[mt][ct][1] * li[1] + __uint_as_float((unsigned)rv[1] << 16);
                o[2] = acc[mt][ct][2] * li[2] + __uint_as_float((unsigned)rv[2] << 16);
                o[3] = acc[mt][ct][3] * li[3] + __uint_as_float((unsigned)rv[3] << 16);
                __builtin_nontemporal_store(o, reinterpret_cast<f32x4*>(ob + (size_t)c * L_ + lbase));
            }
        }
    }
}

extern "C" void kernel_launch(void* const* d_in, const int* in_sizes, int n_in,
                              void* d_out, int out_size, void* d_ws, size_t ws_size,
                              hipStream_t stream) {
    const float* x  = (const float*)d_in[0];
    const float* Wq = (const float*)d_in[1];
    const float* bq = (const float*)d_in[2];
    float* out = (float*)d_out;

    unsigned short* xb   = (unsigned short*)d_ws;                        // B*C*L bf16   = 8 MiB
    unsigned short* xt   = xb + (size_t)B_ * C_ * L_;                    // B*L*C bf16   = 8 MiB
    unsigned short* qbuf = xt + (size_t)B_ * L_ * C_;                    // B*H*L*E bf16 = 8 MiB
    unsigned short* Wb   = qbuf + (size_t)B_ * H_ * L_ * E_;             // 512 KiB
    int* counters = (int*)(Wb + (size_t)H_ * E_ * C_);                   // 16 B (one per batch)

    (void)hipMemsetAsync(counters, 0, 16, stream);
    prep_kernel<<<dim3(32, 8, 4), 256, 0, stream>>>(x, xb, xt);
    wcast_kernel<<<dim3(256), 256, 0, stream>>>(Wq, Wb);
    proj_kernel<<<dim3(32, 8, 4), 256, 0, stream>>>(Wb, bq, xt, qbuf);
    pv_kernel<<<dim3(512), 512, 0, stream>>>(qbuf, xb, out, counters);
}

// Round 19
// 253.800 us; speedup vs baseline: 1.7438x; 1.7065x over previous
//
#include <hip/hip_runtime.h>
#include <hip/hip_bf16.h>

#define B_ 4
#define C_ 512
#define L_ 2048
#define H_ 8
#define E_ 64
// sqrt(0.125 * log2(e)) — folded into Q (and K=Q) so QK^T yields log2-domain scores
#define QSCALE 0.4246609f
#define NUNITS_B 256   // units per batch: 8 h x 32 qt

typedef __attribute__((ext_vector_type(8))) short bf16x8;
typedef __attribute__((ext_vector_type(4))) float f32x4;
typedef __attribute__((ext_vector_type(4))) unsigned short u16x4;

static __device__ __forceinline__ unsigned short f2bf(float f) {
    union { float f; unsigned u; } v; v.f = f;
    unsigned r = v.u + 0x7FFFu + ((v.u >> 16) & 1u);
    return (unsigned short)(r >> 16);
}

// light barrier: make LDS writes visible, do NOT drain vmcnt (loads stay in flight)
#define LBAR() do { asm volatile("s_waitcnt lgkmcnt(0)" ::: "memory"); \
                    __builtin_amdgcn_s_barrier(); } while (0)

// ---------------- Pass A: cast x -> xb (bf16, [b][c][l]) and xt (bf16, [b][l][c]) ----------------
__global__ __launch_bounds__(256) void prep_kernel(const float* __restrict__ x,
                                                   unsigned short* __restrict__ xb,
                                                   unsigned short* __restrict__ xt) {
    const int lt = blockIdx.x, ct = blockIdx.y, b = blockIdx.z;
    const int l0 = lt * 64, c0 = ct * 64;
    const int t = threadIdx.x;
    __shared__ unsigned short T[64 * 72];

    const int cl = t >> 2, lo = (t & 3) * 16;
    const float* src = x + ((size_t)(b * C_ + c0 + cl)) * L_ + l0 + lo;
    unsigned short u[16];
    #pragma unroll
    for (int j = 0; j < 16; j += 4) {
        float4 v = *reinterpret_cast<const float4*>(src + j);
        u[j] = f2bf(v.x); u[j + 1] = f2bf(v.y); u[j + 2] = f2bf(v.z); u[j + 3] = f2bf(v.w);
    }
    unsigned short* xbp = xb + ((size_t)(b * C_ + c0 + cl)) * L_ + l0 + lo;
    reinterpret_cast<uint4*>(xbp)[0] = reinterpret_cast<uint4*>(u)[0];
    reinterpret_cast<uint4*>(xbp)[1] = reinterpret_cast<uint4*>(u)[1];
    reinterpret_cast<uint4*>(&T[cl * 72 + lo])[0] = reinterpret_cast<uint4*>(u)[0];
    reinterpret_cast<uint4*>(&T[cl * 72 + lo + 8])[0] = reinterpret_cast<uint4*>(u)[1];
    __syncthreads();
    const int ll = t >> 2, co = (t & 3) * 16;
    unsigned short v16[16];
    #pragma unroll
    for (int j = 0; j < 16; ++j) v16[j] = T[(co + j) * 72 + ll];
    unsigned short* xtp = xt + ((size_t)b * L_ + l0 + ll) * C_ + c0 + co;
    reinterpret_cast<uint4*>(xtp)[0] = reinterpret_cast<uint4*>(v16)[0];
    reinterpret_cast<uint4*>(xtp)[1] = reinterpret_cast<uint4*>(v16)[1];
}

// ---------------- Pass A2: cast W fp32 -> bf16 ----------------
__global__ __launch_bounds__(256) void wcast_kernel(const float* __restrict__ W,
                                                    unsigned short* __restrict__ Wb) {
    const int i = blockIdx.x * 256 + threadIdx.x;
    float4 v = reinterpret_cast<const float4*>(W)[i];
    union { unsigned short u[4]; unsigned long long ll; } o;
    o.u[0] = f2bf(v.x); o.u[1] = f2bf(v.y); o.u[2] = f2bf(v.z); o.u[3] = f2bf(v.w);
    reinterpret_cast<unsigned long long*>(Wb)[i] = o.ll;
}

// ---------------- Pass B: Q = (W x + b) * QSCALE, bf16 [(b*H+h)][l][e] ----------------
__global__ __launch_bounds__(256) void proj_kernel(const unsigned short* __restrict__ Wb,
                                                   const float* __restrict__ bq,
                                                   const unsigned short* __restrict__ xt,
                                                   unsigned short* __restrict__ qb) {
    const int lt = blockIdx.x, h = blockIdx.y, b = blockIdx.z;
    const int tid = threadIdx.x, w = tid >> 6, lane = tid & 63;
    const int lr = lane & 15, lg = lane >> 4;
    const int l = lt * 64 + w * 16 + lr;
    const int o0 = h * 64;

    f32x4 acc[4] = {};
    const unsigned short* xrow = xt + ((size_t)b * L_ + l) * C_;
    for (int ks = 0; ks < 16; ++ks) {
        bf16x8 bf = *reinterpret_cast<const bf16x8*>(xrow + ks * 32 + lg * 8);
        #pragma unroll
        for (int mt = 0; mt < 4; ++mt) {
            bf16x8 af = *reinterpret_cast<const bf16x8*>(Wb + (size_t)(o0 + mt * 16 + lr) * C_ + ks * 32 + lg * 8);
            acc[mt] = __builtin_amdgcn_mfma_f32_16x16x32_bf16(af, bf, acc[mt], 0, 0, 0);
        }
    }
    const int bh = b * H_ + h;
    unsigned short* qrow = qb + ((size_t)bh * L_ + l) * 64;
    #pragma unroll
    for (int mt = 0; mt < 4; ++mt) {
        const int e0 = mt * 16 + lg * 4;
        const float4 bb = *reinterpret_cast<const float4*>(bq + o0 + e0);
        union { unsigned short u[4]; unsigned long long ll; } o;
        o.u[0] = f2bf((acc[mt][0] + bb.x) * QSCALE);
        o.u[1] = f2bf((acc[mt][1] + bb.y) * QSCALE);
        o.u[2] = f2bf((acc[mt][2] + bb.z) * QSCALE);
        o.u[3] = f2bf((acc[mt][3] + bb.w) * QSCALE);
        *reinterpret_cast<unsigned long long*>(qrow + e0) = o.ll;
    }
}

// ---------------- Pass C: fused attention, KBLK=512, 4-bank V ring (distance 2, R15 body) ----------------
// V loads for 32k-step at k-offset KOFF into bank BK (4 x b128, wave's 64 channels)
#define LDVB(BK, KOFF)                                                                  \
    {                                                                                   \
        _Pragma("unroll")                                                               \
        for (int ct = 0; ct < 4; ++ct)                                                  \
            pvv[BK][ct] = *reinterpret_cast<const bf16x8*>(                             \
                Vbase + (size_t)(c0w + ct * 16 + lr) * L_ + (KOFF) + lg * 8);           \
    }

// PV step S_: consume bank CUR, prefetch step S_+2 into bank NXT (NXT != CUR); 16 MFMAs
#define PV_STEP(CUR, NXT, S_)                                                           \
    {                                                                                   \
        const int s_ = (S_);                                                            \
        if (s_ + 2 < ksmax) LDVB(NXT, k0 + (s_ + 2) * 32)                               \
        bf16x8 pa[4];                                                                   \
        _Pragma("unroll")                                                               \
        for (int mt = 0; mt < 4; ++mt) {                                                \
            const int row = mt * 16 + lr;                                               \
            const int g2 = (s_ * 4 + lg) ^ (lr & 7);                                    \
            pa[mt] = *reinterpret_cast<const bf16x8*>(&P[row * 512 + (g2 << 3)]);       \
        }                                                                               \
        __builtin_amdgcn_s_setprio(1);                                                  \
        _Pragma("unroll")                                                               \
        for (int mt = 0; mt < 4; ++mt)                                                  \
            _Pragma("unroll")                                                           \
            for (int ct = 0; ct < 4; ++ct)                                              \
                acc[mt][ct] = __builtin_amdgcn_mfma_f32_16x16x32_bf16(                  \
                    pa[mt], pvv[CUR][ct], acc[mt][ct], 0, 0, 0);                        \
        __builtin_amdgcn_s_setprio(0);                                                  \
    }

// S phase body: MASKED = 0 (wave fully below diagonal) skips all compare/select VALU
#define S_PHASE(MASKED)                                                                          \
    {                                                                                            \
        bf16x8 kb[4][2];                                                                         \
        _Pragma("unroll")                                                                        \
        for (int ksub = 0; ksub < 4; ++ksub) {                                                   \
            const size_t krow = (size_t)(kw0 + ksub * 16 + lr) * 64;                             \
            kb[ksub][0] = *reinterpret_cast<const bf16x8*>(Qbase + krow + lg * 8);               \
            kb[ksub][1] = *reinterpret_cast<const bf16x8*>(Qbase + krow + 32 + lg * 8);          \
        }                                                                                        \
        _Pragma("unroll")                                                                        \
        for (int nt = 0; nt < 4; ++nt) {                                                         \
            const int qrow = nt * 16 + lr;                                                       \
            bf16x8 aq0 = *reinterpret_cast<const bf16x8*>(&Qt[qrow * 64 + ((lg ^ (lr & 7)) << 3)]);        \
            bf16x8 aq1 = *reinterpret_cast<const bf16x8*>(&Qt[qrow * 64 + (((4 + lg) ^ (lr & 7)) << 3)]);  \
            const int q = q0 + qrow;                                                             \
            _Pragma("unroll")                                                                    \
            for (int ksub = 0; ksub < 4; ++ksub) {                                               \
                f32x4 z = {};                                                                    \
                z = __builtin_amdgcn_mfma_f32_16x16x32_bf16(kb[ksub][0], aq0, z, 0, 0, 0);       \
                z = __builtin_amdgcn_mfma_f32_16x16x32_bf16(kb[ksub][1], aq1, z, 0, 0, 0);       \
                float p0, p1, p2, p3;                                                            \
                if (MASKED) {                                                                    \
                    const int kbase = kw0 + ksub * 16 + lg * 4;                                  \
                    p0 = (kbase + 0 <= q) ? __builtin_amdgcn_exp2f(z[0]) : 0.f;                  \
                    p1 = (kbase + 1 <= q) ? __builtin_amdgcn_exp2f(z[1]) : 0.f;                  \
                    p2 = (kbase + 2 <= q) ? __builtin_amdgcn_exp2f(z[2]) : 0.f;                  \
                    p3 = (kbase + 3 <= q) ? __builtin_amdgcn_exp2f(z[3]) : 0.f;                  \
                } else {                                                                         \
                    p0 = __builtin_amdgcn_exp2f(z[0]);                                           \
                    p1 = __builtin_amdgcn_exp2f(z[1]);                                           \
                    p2 = __builtin_amdgcn_exp2f(z[2]);                                           \
                    p3 = __builtin_amdgcn_exp2f(z[3]);                                           \
                }                                                                                \
                rs[nt] += (p0 + p1) + (p2 + p3);                                                 \
                unsigned r01, r23;                                                               \
                asm("v_cvt_pk_bf16_f32 %0, %1, %2" : "=v"(r01) : "v"(p0), "v"(p1));              \
                asm("v_cvt_pk_bf16_f32 %0, %1, %2" : "=v"(r23) : "v"(p2), "v"(p3));              \
                const int kl = w * 64 + ksub * 16 + lg * 4;                                      \
                const int gg = (kl >> 3) ^ (qrow & 7);                                           \
                const unsigned long long pk = ((unsigned long long)r23 << 32) | r01;             \
                *reinterpret_cast<unsigned long long*>(&P[qrow * 512 + (gg << 3) + (kl & 7)]) = pk; \
            }                                                                                    \
        }                                                                                        \
    }

__global__ __launch_bounds__(512, 2) void pv_kernel(const unsigned short* __restrict__ qb,
                                                    const unsigned short* __restrict__ xb,
                                                    float* __restrict__ out,
                                                    int* __restrict__ counters) {
    const int tid = threadIdx.x, w = tid >> 6, lane = tid & 63;
    const int lr = lane & 15, lg = lane >> 4;
    const int c0w = w * 64;                      // PV: this wave's 64-channel slice
    // batch pinned by blockIdx (XCD round-robin heuristic): 128 blocks per batch
    const int myb = (blockIdx.x & 7) >> 1;

    __shared__ unsigned short Qt[64 * 64];       // swizzled Q tile (8 KB)
    __shared__ unsigned short P[64 * 512];       // 64q x 512k bf16, XOR-swizzled (64 KB)
    __shared__ float rsT[64][8];                 // per-S-wave rowsum partials (2 KB)
    __shared__ int s_u;

    const int b = myb;
    const unsigned short* Vbase = xb + (size_t)b * C_ * L_;

    for (;;) {
        // WAR on s_u only — plain barrier, NO vmcnt drain (NT stores stay in flight)
        __builtin_amdgcn_s_barrier();
        if (tid == 0) s_u = atomicAdd(counters + myb, 1);
        LBAR();   // s_u visible
        const int u = s_u;
        if (u >= NUNITS_B) return;

        // heavy q-tiles first (LPT packing on the per-batch dynamic queue)
        const int qt = 31 - (u >> 3);
        const int h = u & 7;
        const int q0 = qt * 64, qlim = q0 + 63;
        const int nkt = (q0 >> 9) + 1;           // KBLK = 512
        const int bh = b * H_ + h;
        const unsigned short* Qbase = qb + (size_t)bh * L_ * 64;

        // stage Q tile (64 rows x 64 e) into LDS, granule g -> g ^ (row&7)
        {
            const int r = tid >> 3, g = tid & 7;
            bf16x8 v = *reinterpret_cast<const bf16x8*>(Qbase + (size_t)(q0 + r) * 64 + g * 8);
            *reinterpret_cast<bf16x8*>(&Qt[r * 64 + ((g ^ (r & 7)) << 3)]) = v;
        }

        bf16x8 pvv[4][4];                        // 4-bank V ring, distance-2 prefetch
        f32x4 acc[4][4] = {};
        float rs[4] = {0.f, 0.f, 0.f, 0.f};

        LBAR();   // Qt visible

        #pragma unroll 1
        for (int kt = 0; kt < nkt; ++kt) {
            const int k0 = kt * 512;
            const int ksmax = min(16, ((qlim - k0) >> 5) + 1);   // even, 2..16
            const int kw0 = k0 + w * 64;                          // S: wave's 64k slice

            LDVB(0, k0)          // PV steps 0,1 V loads issued under the S phase
            LDVB(1, k0 + 32)

            // ---- S phase: wave computes 64q x 64k slice of S, exp, pack to P ----
            if (kw0 + 63 <= q0) {
                S_PHASE(0)            // fully below diagonal: no mask VALU
            } else if (kw0 <= qlim) {
                S_PHASE(1)            // diagonal slice: masked
            }
            LBAR();   // P visible; V bank-0/1 loads stay in flight

            // ---- PV phase: up to 16 back-to-back steps, 4-bank ring, distance 2 ----
            int s = 0;
            #pragma unroll 1
            for (; s + 4 <= ksmax; s += 4) {
                PV_STEP(0, 2, s)
                PV_STEP(1, 3, s + 1)
                PV_STEP(2, 0, s + 2)
                PV_STEP(3, 1, s + 3)
            }
            if (s < ksmax) {   // remainder 2
                PV_STEP(0, 2, s)
                PV_STEP(1, 3, s + 1)
            }
            LBAR();   // P consumed; next kt's S may overwrite
        }

        // rowsum: reduce over lg, publish per-wave partials, merge
        #pragma unroll
        for (int nt = 0; nt < 4; ++nt) {
            float t0 = __shfl_xor(rs[nt], 16); rs[nt] += t0;
            float t1 = __shfl_xor(rs[nt], 32); rs[nt] += t1;
        }
        if (lg == 0) {
            #pragma unroll
            for (int nt = 0; nt < 4; ++nt) rsT[nt * 16 + lr][w] = rs[nt];
        }
        LBAR();

        // epilogue: li per q, bf16 residual, NT streaming stores
        const unsigned short* xres = xb + (size_t)b * C_ * L_;
        float* ob = out + (size_t)bh * C_ * L_;
        #pragma unroll
        for (int mt = 0; mt < 4; ++mt) {
            f32x4 li;
            #pragma unroll
            for (int r = 0; r < 4; ++r) {
                const f32x4 s0 = *reinterpret_cast<const f32x4*>(&rsT[mt * 16 + lg * 4 + r][0]);
                const f32x4 s1 = *reinterpret_cast<const f32x4*>(&rsT[mt * 16 + lg * 4 + r][4]);
                li[r] = 1.f / (((s0[0] + s0[1]) + (s0[2] + s0[3])) + ((s1[0] + s1[1]) + (s1[2] + s1[3])));
            }
            const int lbase = q0 + mt * 16 + lg * 4;
            #pragma unroll
            for (int ct = 0; ct < 4; ++ct) {
                const int c = c0w + ct * 16 + lr;
                const u16x4 rv = __builtin_nontemporal_load(
                    reinterpret_cast<const u16x4*>(xres + (size_t)c * L_ + lbase));
                f32x4 o;
                o[0] = acc[mt][ct][0] * li[0] + __uint_as_float((unsigned)rv[0] << 16);
                o[1] = acc[mt][ct][1] * li[1] + __uint_as_float((unsigned)rv[1] << 16);
                o[2] = acc[mt][ct][2] * li[2] + __uint_as_float((unsigned)rv[2] << 16);
                o[3] = acc[mt][ct][3] * li[3] + __uint_as_float((unsigned)rv[3] << 16);
                __builtin_nontemporal_store(o, reinterpret_cast<f32x4*>(ob + (size_t)c * L_ + lbase));
            }
        }
    }
}

extern "C" void kernel_launch(void* const* d_in, const int* in_sizes, int n_in,
                              void* d_out, int out_size, void* d_ws, size_t ws_size,
                              hipStream_t stream) {
    const float* x  = (const float*)d_in[0];
    const float* Wq = (const float*)d_in[1];
    const float* bq = (const float*)d_in[2];
    float* out = (float*)d_out;

    unsigned short* xb   = (unsigned short*)d_ws;                        // B*C*L bf16   = 8 MiB
    unsigned short* xt   = xb + (size_t)B_ * C_ * L_;                    // B*L*C bf16   = 8 MiB
    unsigned short* qbuf = xt + (size_t)B_ * L_ * C_;                    // B*H*L*E bf16 = 8 MiB
    unsigned short* Wb   = qbuf + (size_t)B_ * H_ * L_ * E_;             // 512 KiB
    int* counters = (int*)(Wb + (size_t)H_ * E_ * C_);                   // 16 B (one per batch)

    (void)hipMemsetAsync(counters, 0, 16, stream);
    prep_kernel<<<dim3(32, 8, 4), 256, 0, stream>>>(x, xb, xt);
    wcast_kernel<<<dim3(256), 256, 0, stream>>>(Wq, Wb);
    proj_kernel<<<dim3(32, 8, 4), 256, 0, stream>>>(Wb, bq, xt, qbuf);
    pv_kernel<<<dim3(512), 512, 0, stream>>>(qbuf, xb, out, counters);
}